// Round 1
// baseline (241.159 us; speedup 1.0000x reference)
//
#include <hip/hip_runtime.h>

#define BLOCKS  2048
#define THREADS 256
#define WAVES   (THREADS / 64)

// Kernel 1: grid-stride partial reduction over all B*N elements (as float4).
// f(i) = log(v2) - log(v1) + v1/v2 + (mu2-mu1)^2 / v2
__global__ __launch_bounds__(THREADS) void kl_partial_kernel(
    const float4* __restrict__ mu1, const float4* __restrict__ mu2,
    const float4* __restrict__ v1,  const float4* __restrict__ v2,
    float* __restrict__ partial, int n4)
{
    float acc = 0.0f;
    const int stride = gridDim.x * blockDim.x;
    for (int i = blockIdx.x * blockDim.x + threadIdx.x; i < n4; i += stride) {
        float4 a  = mu1[i];
        float4 b  = mu2[i];
        float4 s1 = v1[i];
        float4 s2 = v2[i];

        {
            float r = __builtin_amdgcn_rcpf(s2.x);
            float d = b.x - a.x;
            acc += __logf(s2.x) - __logf(s1.x) + s1.x * r + d * d * r;
        }
        {
            float r = __builtin_amdgcn_rcpf(s2.y);
            float d = b.y - a.y;
            acc += __logf(s2.y) - __logf(s1.y) + s1.y * r + d * d * r;
        }
        {
            float r = __builtin_amdgcn_rcpf(s2.z);
            float d = b.z - a.z;
            acc += __logf(s2.z) - __logf(s1.z) + s1.z * r + d * d * r;
        }
        {
            float r = __builtin_amdgcn_rcpf(s2.w);
            float d = b.w - a.w;
            acc += __logf(s2.w) - __logf(s1.w) + s1.w * r + d * d * r;
        }
    }

    // wave-level reduce (64 lanes)
    #pragma unroll
    for (int off = 32; off > 0; off >>= 1)
        acc += __shfl_down(acc, off, 64);

    __shared__ float sm[WAVES];
    const int lane = threadIdx.x & 63;
    const int wave = threadIdx.x >> 6;
    if (lane == 0) sm[wave] = acc;
    __syncthreads();
    if (threadIdx.x == 0) {
        float s = 0.0f;
        #pragma unroll
        for (int w = 0; w < WAVES; ++w) s += sm[w];
        partial[blockIdx.x] = s;
    }
}

// Kernel 2: reduce the per-block partials (double accumulation) and finish:
// out = 0.5 * (S / B - N)
__global__ __launch_bounds__(THREADS) void kl_final_kernel(
    const float* __restrict__ partial, float* __restrict__ out,
    int nblocks, float invB, float nDim)
{
    double acc = 0.0;
    for (int i = threadIdx.x; i < nblocks; i += THREADS)
        acc += (double)partial[i];

    #pragma unroll
    for (int off = 32; off > 0; off >>= 1)
        acc += __shfl_down(acc, off, 64);

    __shared__ double sm[WAVES];
    const int lane = threadIdx.x & 63;
    const int wave = threadIdx.x >> 6;
    if (lane == 0) sm[wave] = acc;
    __syncthreads();
    if (threadIdx.x == 0) {
        double s = 0.0;
        #pragma unroll
        for (int w = 0; w < WAVES; ++w) s += sm[w];
        out[0] = (float)(0.5 * (s * (double)invB - (double)nDim));
    }
}

extern "C" void kernel_launch(void* const* d_in, const int* in_sizes, int n_in,
                              void* d_out, int out_size, void* d_ws, size_t ws_size,
                              hipStream_t stream)
{
    const float4* mu1 = (const float4*)d_in[0];
    const float4* mu2 = (const float4*)d_in[1];
    const float4* v1  = (const float4*)d_in[2];
    const float4* v2  = (const float4*)d_in[3];

    const long long total = (long long)in_sizes[0];   // B * N = 16384 * 1024
    const int n4 = (int)(total / 4);
    const int B = 16384;
    const int N = 1024;

    float* partial = (float*)d_ws;
    float* out = (float*)d_out;

    kl_partial_kernel<<<BLOCKS, THREADS, 0, stream>>>(mu1, mu2, v1, v2, partial, n4);
    kl_final_kernel<<<1, THREADS, 0, stream>>>(partial, out, BLOCKS,
                                               1.0f / (float)B, (float)N);
}